// Round 9
// baseline (129.605 us; speedup 1.0000x reference)
//
#include <hip/hip_runtime.h>
#include <stdint.h>

#define B_    32
#define CH    64
#define T_    16384
#define NC    129     // noise coeffs
#define NFRM  128     // frames
#define QPAD  136     // padded coeff rows in spec_ws (17*8)
#define MROWS 144     // padded W rows (9 MFMA tiles)
#define FPB   4       // frames per k1 block
#define CHK   16      // frames per k2 chunk (R6-proven)

typedef __attribute__((ext_vector_type(4))) float f32x4;
typedef __attribute__((ext_vector_type(4))) int   i32x4;
typedef __attribute__((ext_vector_type(8))) short bf16x8;

__device__ f32x4 llvm_amdgcn_raw_buffer_load_v4f32(i32x4 rsrc, int voffset, int soffset, int aux) __asm("llvm.amdgcn.raw.buffer.load.v4f32");

__device__ __forceinline__ unsigned short f2bs(float f) {
  union { float f; unsigned u; } v; v.f = f;
  unsigned r = (v.u + 0x7FFFu + ((v.u >> 16) & 1u)) >> 16;
  return (unsigned short)r;
}
__device__ __forceinline__ float b2f(unsigned short s) {
  union { float f; unsigned u; } v; v.u = ((unsigned)s) << 16; return v.f;
}
// truncating bf16 pack of 2 floats -> one dword (single v_perm_b32)
__device__ __forceinline__ unsigned pk2(float lo, float hi) {
  return __builtin_amdgcn_perm(__float_as_uint(hi), __float_as_uint(lo), 0x07060302u);
}
__device__ __forceinline__ i32x4 make_srsrc_wave(const void* p) {
  unsigned long long a = (unsigned long long)p;
  i32x4 r;
  r[0] = __builtin_amdgcn_readfirstlane((int)(unsigned)a);
  r[1] = __builtin_amdgcn_readfirstlane(((int)(unsigned)(a >> 32)) & 0xFFFF);
  r[2] = -1;
  r[3] = 0x00020000;
  return r;
}
// sum across the 16 lanes of each row via DPP row-rotates (pure VALU pipe)
__device__ __forceinline__ float dpp_sum16(float v) {
  float t;
  t = __int_as_float(__builtin_amdgcn_update_dpp(0, __float_as_int(v), 0x121, 0xF, 0xF, false)); v += t;
  t = __int_as_float(__builtin_amdgcn_update_dpp(0, __float_as_int(v), 0x122, 0xF, 0xF, false)); v += t;
  t = __int_as_float(__builtin_amdgcn_update_dpp(0, __float_as_int(v), 0x124, 0xF, 0xF, false)); v += t;
  t = __int_as_float(__builtin_amdgcn_update_dpp(0, __float_as_int(v), 0x128, 0xF, 0xF, false)); v += t;
  return v;
}
// Barrier draining LDS ops only — vmcnt (x prefetch) stays in flight.
__device__ __forceinline__ void bar_lgkm() {
  asm volatile("s_waitcnt lgkmcnt(0)" ::: "memory");
  __builtin_amdgcn_s_barrier();
  asm volatile("" ::: "memory");
}

// ---------------------------------------------------------------------------
// k0: DFT tables (blocks 0..63) + W pack linear bf16 (+ ones-row at q=129
// for the channel-mean-by-MFMA trick) + bias (blocks 64..68).
// ---------------------------------------------------------------------------
__global__ __launch_bounds__(256) void k0_setup(
    unsigned short* __restrict__ T1, unsigned short* __restrict__ T2,
    const float* __restrict__ nw, const float* __restrict__ nb,
    unsigned short* __restrict__ wb_ws, float* __restrict__ bias_ws) {
  int bid = blockIdx.x;
  if (bid < 64) {
    int g = bid * 256 + threadIdx.x;
    int base = g * 8;
    int tab = base >> 16;
    int off = base & 65535;
    int row = off >> 8, col0 = off & 255;
    const float w0 = 6.283185307179586f / 256.f;
    bf16x8 pk;
#pragma unroll
    for (int e = 0; e < 8; ++e) {
      int cq = col0 + e;
      float v;
      if (tab == 0) {  // T1[q][m]
        int q = row, m = cq;
        int idx = (q <= 128) ? ((q * m) & 255) : (((q - 128) * m + 192) & 255);
        v = cosf((float)idx * w0);
      } else {         // T2[n][q]
        int n = row, q = cq;
        float c = (q == 0 || q == 128) ? 1.f : 2.f;
        int idx = (q <= 128) ? ((q * n) & 255) : (((q - 128) * n + 192) & 255);
        v = c * cosf((float)idx * w0);
      }
      pk[e] = (short)f2bs(v);
    }
    *(bf16x8*)((tab ? T2 : T1) + off) = pk;
  } else {
    int t = (bid - 64) * 256 + threadIdx.x;  // 0..1279
    if (t < MROWS * 8) {
      int q = t >> 3, o = t & 7;
      bf16x8 pk;
#pragma unroll
      for (int e = 0; e < 8; ++e) {
        unsigned short v = 0;
        if (q < NC)        v = f2bs(nw[q * 64 + o * 8 + e]);
        else if (q == 129) v = 0x3F80;   // ones-row -> channel sum
        pk[e] = (short)v;
      }
      *(bf16x8*)(wb_ws + q * 64 + o * 8) = pk;
    }
    if (t < MROWS) bias_ws[t] = (t < NC) ? nb[t] : 0.f;
  }
}

// ---------------------------------------------------------------------------
// k1 v8: 256-thr blocks (4 waves), wave w owns q-tiles {w, w+4} (+8 for
// wave 3) -> B-frags read ONCE per wave, reused across tiles. Halves LDS
// read traffic vs v6 and doubles independent blocks/CU (4). Pipeline,
// swizzles, barriers identical to proven v6. FPB=4, grid (32, 32).
// ---------------------------------------------------------------------------
__global__ __launch_bounds__(256, 4) void k1_spec_mean(
    const float* __restrict__ x, const unsigned short* __restrict__ wb_ws,
    const float* __restrict__ bias_ws, float* __restrict__ out,
    unsigned short* __restrict__ spec_ws) {
  __shared__ __align__(16) unsigned short xbT[2][128 * 64];  // 32 KB dbuf

  const int tid = threadIdx.x;
  const int w = tid >> 6, lane = tid & 63;
  const int l15 = lane & 15, l4 = lane >> 4;
  const int g8 = tid >> 5, c16 = tid & 31;   // channel octet, t-quad
  const int b = blockIdx.y;
  const int j0 = blockIdx.x * FPB;

  // W fragments + bias in registers: wave w -> tiles {w, w+4}; wave 3 also 8.
  const int ntile = (w == 3) ? 3 : 2;
  bf16x8 wf[3][2];
  f32x4  bfr[3];
#pragma unroll
  for (int ti = 0; ti < 3; ++ti) {
    if (ti < ntile) {
      int tile = (ti == 0) ? w : (ti == 1) ? (w + 4) : 8;
#pragma unroll
      for (int kt = 0; kt < 2; ++kt)
        wf[ti][kt] = *(const bf16x8*)(wb_ws + (tile * 16 + l15) * 64 + kt * 32 + l4 * 8);
      bfr[ti] = *(const f32x4*)(bias_ws + tile * 16 + l4 * 4);
    }
  }

  i32x4 rx = make_srsrc_wave(x + (size_t)b * CH * T_);
  const int vxbase = (g8 * 8 * T_ + c16 * 4) * 4;  // rows 8*g8.., col c16*4

  f32x4 r[8];
#pragma unroll
  for (int it = 0; it < 8; ++it)
    r[it] = llvm_amdgcn_raw_buffer_load_v4f32(rx, vxbase + j0 * 512, it * (T_ * 4), 0);

#pragma unroll 2
  for (int f = 0; f < FPB; ++f) {
    const int j = j0 + f;
    char* xb = (char*)xbT + (f & 1) * 16384;

    // ---- pack r -> xbT[f&1] (bf16, swizzled): one uint4 per t ----
#pragma unroll
    for (int e = 0; e < 4; ++e) {
      int t = c16 * 4 + e;
      unsigned a = (unsigned)(t * 128 + g8 * 16);
      a ^= (unsigned)(((t ^ (t >> 3)) & 7) << 4);
      uint4 dv = make_uint4(pk2(r[0][e], r[1][e]), pk2(r[2][e], r[3][e]),
                            pk2(r[4][e], r[5][e]), pk2(r[6][e], r[7][e]));
      *(uint4*)(xb + a) = dv;
    }
    if (f < FPB - 1) {
#pragma unroll
      for (int it = 0; it < 8; ++it)
        r[it] = llvm_amdgcn_raw_buffer_load_v4f32(rx, vxbase + (j + 1) * 512, it * (T_ * 4), 0);
    }
    bar_lgkm();  // single barrier per frame; vmcnt NOT drained

    // ---- compute: read B-frags once per tt, apply 2-3 W tiles ----
    f32x4 sum[3];
    sum[0] = (f32x4){0.f, 0.f, 0.f, 0.f};
    sum[1] = (f32x4){0.f, 0.f, 0.f, 0.f};
    sum[2] = (f32x4){0.f, 0.f, 0.f, 0.f};
#pragma unroll
    for (int tt = 0; tt < 8; ++tt) {
      int t = tt * 16 + l15;
      unsigned a0 = (unsigned)(t * 128 + l4 * 16);
      a0 ^= (unsigned)(((t ^ (t >> 3)) & 7) << 4);
      bf16x8 xb0 = *(const bf16x8*)(xb + a0);
      bf16x8 xb1 = *(const bf16x8*)(xb + (a0 ^ 64));
#pragma unroll
      for (int ti = 0; ti < 3; ++ti) {
        if (ti < ntile) {
          f32x4 acc = bfr[ti];
          acc = __builtin_amdgcn_mfma_f32_16x16x32_bf16(wf[ti][0], xb0, acc, 0, 0, 0);
          acc = __builtin_amdgcn_mfma_f32_16x16x32_bf16(wf[ti][1], xb1, acc, 0, 0, 0);
          if (ti == 2 && l4 == 0)  // q=129 ones-row: channel sum -> mean
            out[(size_t)b * T_ + (size_t)j * 128 + tt * 16 + l15] = acc[1] * (1.f / 64.f);
#pragma unroll
          for (int rr = 0; rr < 4; ++rr)
            sum[ti][rr] += __builtin_amdgcn_fmed3f(acc[rr], 0.f, 1.f);
        }
      }
    }
    // frame-mean reduce across the 16 t-cols (l15) via DPP; store 4 bf16.
    // Tile 8 guarded to l4<2: q stays within QPAD (only q<=128 is consumed).
    unsigned short* sp = spec_ws + ((size_t)b * NFRM + j) * QPAD;
#pragma unroll
    for (int ti = 0; ti < 3; ++ti) {
      if (ti < ntile) {
        int tile = (ti == 0) ? w : (ti == 1) ? (w + 4) : 8;
        float s0 = dpp_sum16(sum[ti][0]) * (1.f / 128.f);
        float s1 = dpp_sum16(sum[ti][1]) * (1.f / 128.f);
        float s2 = dpp_sum16(sum[ti][2]) * (1.f / 128.f);
        float s3 = dpp_sum16(sum[ti][3]) * (1.f / 128.f);
        if (l15 == 0 && (tile != 8 || l4 < 2)) {
          uint2 pv = make_uint2(pk2(s0, s1), pk2(s2, s3));
          *(uint2*)(sp + tile * 16 + l4 * 4) = pv;
        }
      }
    }
  }
}

// ---------------------------------------------------------------------------
// k2 (R6-proven, CHK=16): chunk = 16 frames -> grid (8, 32) = 256 blocks.
// Slots s=0..16 map to frames j = c*16-1+s (slot 0 = tail provider, spec=0
// for j<0). N padded to 32 slots (s>=17 zero).
// ---------------------------------------------------------------------------
__global__ __launch_bounds__(512) void k2_noise(
    const float* __restrict__ white, const unsigned short* __restrict__ spec_ws,
    const unsigned short* __restrict__ T1, const unsigned short* __restrict__ T2,
    const float* __restrict__ nf_p, float* __restrict__ out) {
  __shared__ __align__(16) unsigned short wn[4224];
  __shared__ __align__(16) unsigned short spec_l[32 * QPAD];
  __shared__ __align__(16) unsigned short G[32 * 256];
  __shared__ __align__(16) unsigned short audio[256 * 33];

  const int c = blockIdx.x, b = blockIdx.y;
  const int jb = c * CHK - 1;
  const int tid = threadIdx.x;
  const int lane = tid & 63, w = tid >> 6;
  const int l15 = lane & 15, l4 = lane >> 4;

  for (int rc = tid; rc < 528; rc += 512) {
    int g0 = jb * 128 + rc * 8;
    bf16x8 pk;
    if (rc < 288 && (unsigned)g0 < (unsigned)T_) {
      const float* wp = white + (size_t)b * T_ + g0;
      union { unsigned u[4]; bf16x8 h; } t;
#pragma unroll
      for (int p = 0; p < 4; ++p) t.u[p] = pk2(wp[2 * p], wp[2 * p + 1]);
      pk = t.h;
    } else {
#pragma unroll
      for (int e = 0; e < 8; ++e) pk[e] = 0;
    }
    unsigned a = rc * 16;
    a ^= ((a >> 8) & 7) << 4;
    *(bf16x8*)((char*)wn + a) = pk;
  }
  for (int ec = tid; ec < 32 * 17; ec += 512) {
    int s = ec / 17, cr = ec % 17;
    int jj = jb + s;
    uint4 vv = make_uint4(0u, 0u, 0u, 0u);
    if (s < 17 && (unsigned)jj < 128u)
      vv = *(const uint4*)(spec_ws + ((size_t)b * NFRM + jj) * QPAD + cr * 8);
    *(uint4*)(spec_l + s * QPAD + cr * 8) = vv;
  }
  __syncthreads();

  const f32x4 fz = {0.f, 0.f, 0.f, 0.f};
  f32x4 acc[2][2];
#pragma unroll
  for (int mi = 0; mi < 2; ++mi)
#pragma unroll
    for (int nt = 0; nt < 2; ++nt) acc[mi][nt] = fz;
#pragma unroll
  for (int kt = 0; kt < 8; ++kt) {
    bf16x8 bfr[2];
#pragma unroll
    for (int nt = 0; nt < 2; ++nt) {
      int s = nt * 16 + l15;
      unsigned a = s * 256 + kt * 64 + l4 * 16;
      a ^= ((a >> 8) & 7) << 4;
      bfr[nt] = *(const bf16x8*)((const char*)wn + a);
    }
#pragma unroll
    for (int mi = 0; mi < 2; ++mi) {
      int q = (2 * w + mi) * 16 + l15;
      bf16x8 afr = *(const bf16x8*)(T1 + q * 256 + kt * 32 + l4 * 8);
#pragma unroll
      for (int nt = 0; nt < 2; ++nt)
        acc[mi][nt] = __builtin_amdgcn_mfma_f32_16x16x32_bf16(afr, bfr[nt], acc[mi][nt], 0, 0, 0);
    }
  }
#pragma unroll
  for (int mi = 0; mi < 2; ++mi) {
    int qbase = (2 * w + mi) * 16 + l4 * 4;
#pragma unroll
    for (int nt = 0; nt < 2; ++nt) {
      int s = nt * 16 + l15;
#pragma unroll
      for (int rp = 0; rp < 2; ++rp) {
        int q0 = qbase + rp * 2;
        int kk0 = (q0 <= 128) ? q0 : q0 - 128;
        int kk1 = (q0 + 1 <= 128) ? q0 + 1 : q0 - 127;
        float s0 = b2f(spec_l[s * QPAD + kk0]);
        float s1 = b2f(spec_l[s * QPAD + kk1]);
        unsigned pw = pk2(acc[mi][nt][rp * 2] * s0, acc[mi][nt][rp * 2 + 1] * s1);
        unsigned a = s * 512 + q0 * 2;
        a ^= ((a >> 9) & 7) << 4;
        *(unsigned*)((char*)G + a) = pw;
      }
    }
  }
  __syncthreads();

  f32x4 acc2[2][2];
#pragma unroll
  for (int mi = 0; mi < 2; ++mi)
#pragma unroll
    for (int nt = 0; nt < 2; ++nt) acc2[mi][nt] = fz;
#pragma unroll
  for (int kt = 0; kt < 8; ++kt) {
    bf16x8 bfr[2];
#pragma unroll
    for (int nt = 0; nt < 2; ++nt) {
      int s = nt * 16 + l15;
      unsigned a = s * 512 + kt * 64 + l4 * 16;
      a ^= ((a >> 9) & 7) << 4;
      bfr[nt] = *(const bf16x8*)((const char*)G + a);
    }
#pragma unroll
    for (int mi = 0; mi < 2; ++mi) {
      int n = (2 * w + mi) * 16 + l15;
      bf16x8 afr = *(const bf16x8*)(T2 + n * 256 + kt * 32 + l4 * 8);
#pragma unroll
      for (int nt = 0; nt < 2; ++nt)
        acc2[mi][nt] = __builtin_amdgcn_mfma_f32_16x16x32_bf16(afr, bfr[nt], acc2[mi][nt], 0, 0, 0);
    }
  }
#pragma unroll
  for (int mi = 0; mi < 2; ++mi)
#pragma unroll
    for (int nt = 0; nt < 2; ++nt)
#pragma unroll
      for (int r = 0; r < 4; ++r) {
        int n = (2 * w + mi) * 16 + l4 * 4 + r;
        int s = nt * 16 + l15;
        audio[n * 33 + s] = f2bs(acc2[mi][nt][r]);
      }
  __syncthreads();

  const float cf = nf_p[0] * (1.f / 256.f);
  {
    int t0 = tid * 4;
    int n = t0 & 127, jl = t0 >> 7;
    int s1 = jl + 1;
    size_t o = (size_t)b * T_ + (size_t)c * (CHK * 128) + t0;
    f32x4 ov = *(f32x4*)(out + o);
#pragma unroll
    for (int e = 0; e < 4; ++e) {
      float a1 = b2f(audio[(n + e) * 33 + s1]);
      float a2 = b2f(audio[(n + e + 128) * 33 + jl]);
      ov[e] += cf * (a1 + a2);
    }
    *(f32x4*)(out + o) = ov;
  }
}

// ---------------------------------------------------------------------------
extern "C" void kernel_launch(void* const* d_in, const int* in_sizes, int n_in,
                              void* d_out, int out_size, void* d_ws, size_t ws_size,
                              hipStream_t stream) {
  (void)in_sizes; (void)n_in; (void)out_size; (void)ws_size;
  const float* x            = (const float*)d_in[0];
  const float* noise_w      = (const float*)d_in[5];
  const float* noise_b      = (const float*)d_in[6];
  const float* noise_factor = (const float*)d_in[7];
  const float* white        = (const float*)d_in[8];
  float* out = (float*)d_out;

  unsigned short* T1    = (unsigned short*)d_ws;             // 65536 bf16
  unsigned short* T2    = T1 + 65536;                        // 65536 bf16
  unsigned short* spec  = T2 + 65536;                        // 32*128*136 bf16
  unsigned short* wb_ws = spec + (size_t)B_ * NFRM * QPAD;   // 144*64 bf16 linear
  float*          bias_ws = (float*)(wb_ws + MROWS * 64);    // 144 f32

  k0_setup<<<69, 256, 0, stream>>>(T1, T2, noise_w, noise_b, wb_ws, bias_ws);
  k1_spec_mean<<<dim3(NFRM / FPB, B_), 256, 0, stream>>>(x, wb_ws, bias_ws, out, spec);
  k2_noise<<<dim3(T_ / (CHK * 128), B_), 512, 0, stream>>>(white, spec, T1, T2, noise_factor, out);
}

// Round 10
// 46.535 us; speedup vs baseline: 2.7851x; 2.7851x over previous
//
#include <hip/hip_runtime.h>
#include <stdint.h>

#define B_    32
#define CH    64
#define T_    16384
#define NC    129     // noise coeffs
#define NFRM  128     // frames
#define QPAD  136     // padded coeff rows in spec_ws (17*8)
#define MROWS 144     // padded W rows (9 MFMA tiles)
#define FPB   4       // frames per k1 block (R10: was 8 in R6)
#define CHK   16      // frames per k2 chunk (R6-proven)

typedef __attribute__((ext_vector_type(4))) float f32x4;
typedef __attribute__((ext_vector_type(4))) int   i32x4;
typedef __attribute__((ext_vector_type(8))) short bf16x8;

__device__ f32x4 llvm_amdgcn_raw_buffer_load_v4f32(i32x4 rsrc, int voffset, int soffset, int aux) __asm("llvm.amdgcn.raw.buffer.load.v4f32");

__device__ __forceinline__ unsigned short f2bs(float f) {
  union { float f; unsigned u; } v; v.f = f;
  unsigned r = (v.u + 0x7FFFu + ((v.u >> 16) & 1u)) >> 16;
  return (unsigned short)r;
}
__device__ __forceinline__ float b2f(unsigned short s) {
  union { float f; unsigned u; } v; v.u = ((unsigned)s) << 16; return v.f;
}
// truncating bf16 pack of 2 floats -> one dword (single v_perm_b32)
__device__ __forceinline__ unsigned pk2(float lo, float hi) {
  return __builtin_amdgcn_perm(__float_as_uint(hi), __float_as_uint(lo), 0x07060302u);
}
__device__ __forceinline__ i32x4 make_srsrc_wave(const void* p) {
  unsigned long long a = (unsigned long long)p;
  i32x4 r;
  r[0] = __builtin_amdgcn_readfirstlane((int)(unsigned)a);
  r[1] = __builtin_amdgcn_readfirstlane(((int)(unsigned)(a >> 32)) & 0xFFFF);
  r[2] = -1;
  r[3] = 0x00020000;
  return r;
}
// sum across the 16 lanes of each row via DPP row-rotates (pure VALU pipe)
__device__ __forceinline__ float dpp_sum16(float v) {
  float t;
  t = __int_as_float(__builtin_amdgcn_update_dpp(0, __float_as_int(v), 0x121, 0xF, 0xF, false)); v += t;
  t = __int_as_float(__builtin_amdgcn_update_dpp(0, __float_as_int(v), 0x122, 0xF, 0xF, false)); v += t;
  t = __int_as_float(__builtin_amdgcn_update_dpp(0, __float_as_int(v), 0x124, 0xF, 0xF, false)); v += t;
  t = __int_as_float(__builtin_amdgcn_update_dpp(0, __float_as_int(v), 0x128, 0xF, 0xF, false)); v += t;
  return v;
}
// Barrier draining LDS ops only — vmcnt (x prefetch) stays in flight.
__device__ __forceinline__ void bar_lgkm() {
  asm volatile("s_waitcnt lgkmcnt(0)" ::: "memory");
  __builtin_amdgcn_s_barrier();
  asm volatile("" ::: "memory");
}

// ---------------------------------------------------------------------------
// k0: DFT tables (blocks 0..63) + W pack linear bf16 (+ ones-row at q=129
// for the channel-mean-by-MFMA trick) + bias (blocks 64..68).
// ---------------------------------------------------------------------------
__global__ __launch_bounds__(256) void k0_setup(
    unsigned short* __restrict__ T1, unsigned short* __restrict__ T2,
    const float* __restrict__ nw, const float* __restrict__ nb,
    unsigned short* __restrict__ wb_ws, float* __restrict__ bias_ws) {
  int bid = blockIdx.x;
  if (bid < 64) {
    int g = bid * 256 + threadIdx.x;
    int base = g * 8;
    int tab = base >> 16;
    int off = base & 65535;
    int row = off >> 8, col0 = off & 255;
    const float w0 = 6.283185307179586f / 256.f;
    bf16x8 pk;
#pragma unroll
    for (int e = 0; e < 8; ++e) {
      int cq = col0 + e;
      float v;
      if (tab == 0) {  // T1[q][m]
        int q = row, m = cq;
        int idx = (q <= 128) ? ((q * m) & 255) : (((q - 128) * m + 192) & 255);
        v = cosf((float)idx * w0);
      } else {         // T2[n][q]
        int n = row, q = cq;
        float c = (q == 0 || q == 128) ? 1.f : 2.f;
        int idx = (q <= 128) ? ((q * n) & 255) : (((q - 128) * n + 192) & 255);
        v = c * cosf((float)idx * w0);
      }
      pk[e] = (short)f2bs(v);
    }
    *(bf16x8*)((tab ? T2 : T1) + off) = pk;
  } else {
    int t = (bid - 64) * 256 + threadIdx.x;  // 0..1279
    if (t < MROWS * 8) {
      int q = t >> 3, o = t & 7;
      bf16x8 pk;
#pragma unroll
      for (int e = 0; e < 8; ++e) {
        unsigned short v = 0;
        if (q < NC)        v = f2bs(nw[q * 64 + o * 8 + e]);
        else if (q == 129) v = 0x3F80;   // ones-row -> channel sum
        pk[e] = (short)v;
      }
      *(bf16x8*)(wb_ws + q * 64 + o * 8) = pk;
    }
    if (t < MROWS) bias_ws[t] = (t < NC) ? nb[t] : 0.f;
  }
}

// ---------------------------------------------------------------------------
// k1 v6 (R6-proven structure; FPB=4): q-split waves, W+bias in registers,
// LDS = x-transpose dbuf ONLY, one lgkm-barrier per frame, spec frame-sum
// wave-local (dpp), mean via the W ones-row (q=129, wave 0 / tile 8).
// Block = 512 thr (8 waves) x 4 frames; grid (32, 32) = 1024 blocks.
// ---------------------------------------------------------------------------
__global__ __launch_bounds__(512, 4) void k1_spec_mean(
    const float* __restrict__ x, const unsigned short* __restrict__ wb_ws,
    const float* __restrict__ bias_ws, float* __restrict__ out,
    unsigned short* __restrict__ spec_ws) {
  __shared__ __align__(16) unsigned short xbT[2][128 * 64];  // 32 KB dbuf

  const int tid = threadIdx.x;
  const int w = tid >> 6, lane = tid & 63;
  const int l15 = lane & 15, l4 = lane >> 4;
  const int g = tid >> 5, c16 = tid & 31;
  const int b = blockIdx.y;
  const int j0 = blockIdx.x * FPB;

  // W fragments + bias in registers: wave w owns tile w; wave 0 also tile 8.
  const int ntile = (w == 0) ? 2 : 1;
  bf16x8 wf[2][2];
  f32x4  bfr[2];
#pragma unroll
  for (int ti = 0; ti < 2; ++ti) {
    if (ti < ntile) {
      int tile = (ti == 0) ? w : 8;
#pragma unroll
      for (int kt = 0; kt < 2; ++kt)
        wf[ti][kt] = *(const bf16x8*)(wb_ws + (tile * 16 + l15) * 64 + kt * 32 + l4 * 8);
      bfr[ti] = *(const f32x4*)(bias_ws + tile * 16 + l4 * 4);
    }
  }

  i32x4 rx = make_srsrc_wave(x + (size_t)b * CH * T_);
  const int vxbase = (g * 4 * T_ + c16 * 4) * 4;  // rows 4g..4g+3, col c16*4

  f32x4 r[4];
#pragma unroll
  for (int it = 0; it < 4; ++it)
    r[it] = llvm_amdgcn_raw_buffer_load_v4f32(rx, vxbase + j0 * 512, it * (T_ * 4), 0);

#pragma unroll 2
  for (int f = 0; f < FPB; ++f) {
    const int j = j0 + f;
    char* xb = (char*)xbT + (f & 1) * 16384;

    // ---- pack r -> xbT[f&1] (bf16, swizzled), then prefetch frame f+1 ----
    {
      const int o8 = g >> 1, h = g & 1;
#pragma unroll
      for (int e = 0; e < 4; ++e) {
        int t = c16 * 4 + e;
        unsigned a = (unsigned)(t * 128 + o8 * 16 + h * 8);
        a ^= (unsigned)(((t ^ (t >> 3)) & 7) << 4);
        uint2 dv = make_uint2(pk2(r[0][e], r[1][e]), pk2(r[2][e], r[3][e]));
        *(uint2*)(xb + a) = dv;
      }
    }
    if (f < FPB - 1) {
#pragma unroll
      for (int it = 0; it < 4; ++it)
        r[it] = llvm_amdgcn_raw_buffer_load_v4f32(rx, vxbase + (j + 1) * 512, it * (T_ * 4), 0);
    }
    bar_lgkm();  // single barrier per frame; vmcnt NOT drained

    // ---- compute: D[q][t] = W*x^T, clip, wave-local frame-sum ----
    f32x4 sum[2];
    sum[0] = (f32x4){0.f, 0.f, 0.f, 0.f};
    sum[1] = (f32x4){0.f, 0.f, 0.f, 0.f};
#pragma unroll
    for (int tt = 0; tt < 8; ++tt) {
      int t = tt * 16 + l15;
      unsigned a0 = (unsigned)(t * 128 + l4 * 16);
      a0 ^= (unsigned)(((t ^ (t >> 3)) & 7) << 4);
      bf16x8 xb0 = *(const bf16x8*)(xb + a0);
      bf16x8 xb1 = *(const bf16x8*)(xb + (a0 ^ 64));
#pragma unroll
      for (int ti = 0; ti < 2; ++ti) {
        if (ti < ntile) {
          f32x4 acc = bfr[ti];
          acc = __builtin_amdgcn_mfma_f32_16x16x32_bf16(wf[ti][0], xb0, acc, 0, 0, 0);
          acc = __builtin_amdgcn_mfma_f32_16x16x32_bf16(wf[ti][1], xb1, acc, 0, 0, 0);
          if (ti == 1 && l4 == 0)  // q=129 ones-row: channel sum -> mean
            out[(size_t)b * T_ + (size_t)j * 128 + tt * 16 + l15] = acc[1] * (1.f / 64.f);
#pragma unroll
          for (int rr = 0; rr < 4; ++rr)
            sum[ti][rr] += __builtin_amdgcn_fmed3f(acc[rr], 0.f, 1.f);
        }
      }
    }
    // frame-mean reduce across the 16 t-cols (l15) via DPP; store 4 bf16.
    // Tile 8 guarded to l4<2 so q stays within QPAD (only q<=128 consumed).
    unsigned short* sp = spec_ws + ((size_t)b * NFRM + j) * QPAD;
#pragma unroll
    for (int ti = 0; ti < 2; ++ti) {
      if (ti < ntile) {
        int tile = (ti == 0) ? w : 8;
        float s0 = dpp_sum16(sum[ti][0]) * (1.f / 128.f);
        float s1 = dpp_sum16(sum[ti][1]) * (1.f / 128.f);
        float s2 = dpp_sum16(sum[ti][2]) * (1.f / 128.f);
        float s3 = dpp_sum16(sum[ti][3]) * (1.f / 128.f);
        if (l15 == 0 && (tile != 8 || l4 < 2)) {
          uint2 pv = make_uint2(pk2(s0, s1), pk2(s2, s3));
          *(uint2*)(sp + tile * 16 + l4 * 4) = pv;
        }
      }
    }
  }
}

// ---------------------------------------------------------------------------
// k2 (R6-proven, CHK=16): chunk = 16 frames -> grid (8, 32) = 256 blocks.
// Slots s=0..16 map to frames j = c*16-1+s (slot 0 = tail provider, spec=0
// for j<0). N padded to 32 slots (s>=17 zero).
// ---------------------------------------------------------------------------
__global__ __launch_bounds__(512) void k2_noise(
    const float* __restrict__ white, const unsigned short* __restrict__ spec_ws,
    const unsigned short* __restrict__ T1, const unsigned short* __restrict__ T2,
    const float* __restrict__ nf_p, float* __restrict__ out) {
  __shared__ __align__(16) unsigned short wn[4224];
  __shared__ __align__(16) unsigned short spec_l[32 * QPAD];
  __shared__ __align__(16) unsigned short G[32 * 256];
  __shared__ __align__(16) unsigned short audio[256 * 33];

  const int c = blockIdx.x, b = blockIdx.y;
  const int jb = c * CHK - 1;
  const int tid = threadIdx.x;
  const int lane = tid & 63, w = tid >> 6;
  const int l15 = lane & 15, l4 = lane >> 4;

  for (int rc = tid; rc < 528; rc += 512) {
    int g0 = jb * 128 + rc * 8;
    bf16x8 pk;
    if (rc < 288 && (unsigned)g0 < (unsigned)T_) {
      const float* wp = white + (size_t)b * T_ + g0;
      union { unsigned u[4]; bf16x8 h; } t;
#pragma unroll
      for (int p = 0; p < 4; ++p) t.u[p] = pk2(wp[2 * p], wp[2 * p + 1]);
      pk = t.h;
    } else {
#pragma unroll
      for (int e = 0; e < 8; ++e) pk[e] = 0;
    }
    unsigned a = rc * 16;
    a ^= ((a >> 8) & 7) << 4;
    *(bf16x8*)((char*)wn + a) = pk;
  }
  for (int ec = tid; ec < 32 * 17; ec += 512) {
    int s = ec / 17, cr = ec % 17;
    int jj = jb + s;
    uint4 vv = make_uint4(0u, 0u, 0u, 0u);
    if (s < 17 && (unsigned)jj < 128u)
      vv = *(const uint4*)(spec_ws + ((size_t)b * NFRM + jj) * QPAD + cr * 8);
    *(uint4*)(spec_l + s * QPAD + cr * 8) = vv;
  }
  __syncthreads();

  const f32x4 fz = {0.f, 0.f, 0.f, 0.f};
  f32x4 acc[2][2];
#pragma unroll
  for (int mi = 0; mi < 2; ++mi)
#pragma unroll
    for (int nt = 0; nt < 2; ++nt) acc[mi][nt] = fz;
#pragma unroll
  for (int kt = 0; kt < 8; ++kt) {
    bf16x8 bfr[2];
#pragma unroll
    for (int nt = 0; nt < 2; ++nt) {
      int s = nt * 16 + l15;
      unsigned a = s * 256 + kt * 64 + l4 * 16;
      a ^= ((a >> 8) & 7) << 4;
      bfr[nt] = *(const bf16x8*)((const char*)wn + a);
    }
#pragma unroll
    for (int mi = 0; mi < 2; ++mi) {
      int q = (2 * w + mi) * 16 + l15;
      bf16x8 afr = *(const bf16x8*)(T1 + q * 256 + kt * 32 + l4 * 8);
#pragma unroll
      for (int nt = 0; nt < 2; ++nt)
        acc[mi][nt] = __builtin_amdgcn_mfma_f32_16x16x32_bf16(afr, bfr[nt], acc[mi][nt], 0, 0, 0);
    }
  }
#pragma unroll
  for (int mi = 0; mi < 2; ++mi) {
    int qbase = (2 * w + mi) * 16 + l4 * 4;
#pragma unroll
    for (int nt = 0; nt < 2; ++nt) {
      int s = nt * 16 + l15;
#pragma unroll
      for (int rp = 0; rp < 2; ++rp) {
        int q0 = qbase + rp * 2;
        int kk0 = (q0 <= 128) ? q0 : q0 - 128;
        int kk1 = (q0 + 1 <= 128) ? q0 + 1 : q0 - 127;
        float s0 = b2f(spec_l[s * QPAD + kk0]);
        float s1 = b2f(spec_l[s * QPAD + kk1]);
        unsigned pw = pk2(acc[mi][nt][rp * 2] * s0, acc[mi][nt][rp * 2 + 1] * s1);
        unsigned a = s * 512 + q0 * 2;
        a ^= ((a >> 9) & 7) << 4;
        *(unsigned*)((char*)G + a) = pw;
      }
    }
  }
  __syncthreads();

  f32x4 acc2[2][2];
#pragma unroll
  for (int mi = 0; mi < 2; ++mi)
#pragma unroll
    for (int nt = 0; nt < 2; ++nt) acc2[mi][nt] = fz;
#pragma unroll
  for (int kt = 0; kt < 8; ++kt) {
    bf16x8 bfr[2];
#pragma unroll
    for (int nt = 0; nt < 2; ++nt) {
      int s = nt * 16 + l15;
      unsigned a = s * 512 + kt * 64 + l4 * 16;
      a ^= ((a >> 9) & 7) << 4;
      bfr[nt] = *(const bf16x8*)((const char*)G + a);
    }
#pragma unroll
    for (int mi = 0; mi < 2; ++mi) {
      int n = (2 * w + mi) * 16 + l15;
      bf16x8 afr = *(const bf16x8*)(T2 + n * 256 + kt * 32 + l4 * 8);
#pragma unroll
      for (int nt = 0; nt < 2; ++nt)
        acc2[mi][nt] = __builtin_amdgcn_mfma_f32_16x16x32_bf16(afr, bfr[nt], acc2[mi][nt], 0, 0, 0);
    }
  }
#pragma unroll
  for (int mi = 0; mi < 2; ++mi)
#pragma unroll
    for (int nt = 0; nt < 2; ++nt)
#pragma unroll
      for (int r = 0; r < 4; ++r) {
        int n = (2 * w + mi) * 16 + l4 * 4 + r;
        int s = nt * 16 + l15;
        audio[n * 33 + s] = f2bs(acc2[mi][nt][r]);
      }
  __syncthreads();

  const float cf = nf_p[0] * (1.f / 256.f);
  {
    int t0 = tid * 4;
    int n = t0 & 127, jl = t0 >> 7;
    int s1 = jl + 1;
    size_t o = (size_t)b * T_ + (size_t)c * (CHK * 128) + t0;
    f32x4 ov = *(f32x4*)(out + o);
#pragma unroll
    for (int e = 0; e < 4; ++e) {
      float a1 = b2f(audio[(n + e) * 33 + s1]);
      float a2 = b2f(audio[(n + e + 128) * 33 + jl]);
      ov[e] += cf * (a1 + a2);
    }
    *(f32x4*)(out + o) = ov;
  }
}

// ---------------------------------------------------------------------------
extern "C" void kernel_launch(void* const* d_in, const int* in_sizes, int n_in,
                              void* d_out, int out_size, void* d_ws, size_t ws_size,
                              hipStream_t stream) {
  (void)in_sizes; (void)n_in; (void)out_size; (void)ws_size;
  const float* x            = (const float*)d_in[0];
  const float* noise_w      = (const float*)d_in[5];
  const float* noise_b      = (const float*)d_in[6];
  const float* noise_factor = (const float*)d_in[7];
  const float* white        = (const float*)d_in[8];
  float* out = (float*)d_out;

  unsigned short* T1    = (unsigned short*)d_ws;             // 65536 bf16
  unsigned short* T2    = T1 + 65536;                        // 65536 bf16
  unsigned short* spec  = T2 + 65536;                        // 32*128*136 bf16
  unsigned short* wb_ws = spec + (size_t)B_ * NFRM * QPAD;   // 144*64 bf16 linear
  float*          bias_ws = (float*)(wb_ws + MROWS * 64);    // 144 f32

  k0_setup<<<69, 256, 0, stream>>>(T1, T2, noise_w, noise_b, wb_ws, bias_ws);
  k1_spec_mean<<<dim3(NFRM / FPB, B_), 512, 0, stream>>>(x, wb_ws, bias_ws, out, spec);
  k2_noise<<<dim3(T_ / (CHK * 128), B_), 512, 0, stream>>>(white, spec, T1, T2, noise_factor, out);
}

// Round 11
// 44.695 us; speedup vs baseline: 2.8998x; 1.0412x over previous
//
#include <hip/hip_runtime.h>
#include <stdint.h>

#define B_    32
#define CH    64
#define T_    16384
#define NC    129     // noise coeffs
#define NFRM  128     // frames
#define QPAD  136     // padded coeff rows in spec_ws (17*8)
#define MROWS 144     // padded W rows (9 MFMA tiles)
#define FPB   8       // frames per k1 block (R6-proven)
#define CHK   16      // frames per k2 chunk (R6-proven)

typedef __attribute__((ext_vector_type(4))) float f32x4;
typedef __attribute__((ext_vector_type(4))) int   i32x4;
typedef __attribute__((ext_vector_type(8))) short bf16x8;

__device__ f32x4 llvm_amdgcn_raw_buffer_load_v4f32(i32x4 rsrc, int voffset, int soffset, int aux) __asm("llvm.amdgcn.raw.buffer.load.v4f32");

__device__ __forceinline__ unsigned short f2bs(float f) {
  union { float f; unsigned u; } v; v.f = f;
  unsigned r = (v.u + 0x7FFFu + ((v.u >> 16) & 1u)) >> 16;
  return (unsigned short)r;
}
__device__ __forceinline__ float b2f(unsigned short s) {
  union { float f; unsigned u; } v; v.u = ((unsigned)s) << 16; return v.f;
}
// truncating bf16 pack of 2 floats -> one dword (single v_perm_b32)
__device__ __forceinline__ unsigned pk2(float lo, float hi) {
  return __builtin_amdgcn_perm(__float_as_uint(hi), __float_as_uint(lo), 0x07060302u);
}
__device__ __forceinline__ i32x4 make_srsrc_wave(const void* p) {
  unsigned long long a = (unsigned long long)p;
  i32x4 r;
  r[0] = __builtin_amdgcn_readfirstlane((int)(unsigned)a);
  r[1] = __builtin_amdgcn_readfirstlane(((int)(unsigned)(a >> 32)) & 0xFFFF);
  r[2] = -1;
  r[3] = 0x00020000;
  return r;
}
// sum across the 16 lanes of each row via DPP row-rotates (pure VALU pipe)
__device__ __forceinline__ float dpp_sum16(float v) {
  float t;
  t = __int_as_float(__builtin_amdgcn_update_dpp(0, __float_as_int(v), 0x121, 0xF, 0xF, false)); v += t;
  t = __int_as_float(__builtin_amdgcn_update_dpp(0, __float_as_int(v), 0x122, 0xF, 0xF, false)); v += t;
  t = __int_as_float(__builtin_amdgcn_update_dpp(0, __float_as_int(v), 0x124, 0xF, 0xF, false)); v += t;
  t = __int_as_float(__builtin_amdgcn_update_dpp(0, __float_as_int(v), 0x128, 0xF, 0xF, false)); v += t;
  return v;
}
// Barrier draining LDS ops only — vmcnt (x prefetch) stays in flight.
__device__ __forceinline__ void bar_lgkm() {
  asm volatile("s_waitcnt lgkmcnt(0)" ::: "memory");
  __builtin_amdgcn_s_barrier();
  asm volatile("" ::: "memory");
}

// ---------------------------------------------------------------------------
// k0: DFT tables (blocks 0..63) + W pack linear bf16 (+ ones-row at q=129
// for the channel-mean-by-MFMA trick) + bias (blocks 64..68).
// ---------------------------------------------------------------------------
__global__ __launch_bounds__(256) void k0_setup(
    unsigned short* __restrict__ T1, unsigned short* __restrict__ T2,
    const float* __restrict__ nw, const float* __restrict__ nb,
    unsigned short* __restrict__ wb_ws, float* __restrict__ bias_ws) {
  int bid = blockIdx.x;
  if (bid < 64) {
    int g = bid * 256 + threadIdx.x;
    int base = g * 8;
    int tab = base >> 16;
    int off = base & 65535;
    int row = off >> 8, col0 = off & 255;
    const float w0 = 6.283185307179586f / 256.f;
    bf16x8 pk;
#pragma unroll
    for (int e = 0; e < 8; ++e) {
      int cq = col0 + e;
      float v;
      if (tab == 0) {  // T1[q][m]
        int q = row, m = cq;
        int idx = (q <= 128) ? ((q * m) & 255) : (((q - 128) * m + 192) & 255);
        v = cosf((float)idx * w0);
      } else {         // T2[n][q]
        int n = row, q = cq;
        float c = (q == 0 || q == 128) ? 1.f : 2.f;
        int idx = (q <= 128) ? ((q * n) & 255) : (((q - 128) * n + 192) & 255);
        v = c * cosf((float)idx * w0);
      }
      pk[e] = (short)f2bs(v);
    }
    *(bf16x8*)((tab ? T2 : T1) + off) = pk;
  } else {
    int t = (bid - 64) * 256 + threadIdx.x;  // 0..1279
    if (t < MROWS * 8) {
      int q = t >> 3, o = t & 7;
      bf16x8 pk;
#pragma unroll
      for (int e = 0; e < 8; ++e) {
        unsigned short v = 0;
        if (q < NC)        v = f2bs(nw[q * 64 + o * 8 + e]);
        else if (q == 129) v = 0x3F80;   // ones-row -> channel sum
        pk[e] = (short)v;
      }
      *(bf16x8*)(wb_ws + q * 64 + o * 8) = pk;
    }
    if (t < MROWS) bias_ws[t] = (t < NC) ? nb[t] : 0.f;
  }
}

// ---------------------------------------------------------------------------
// k1 v6 (R6-proven, best measured): q-split waves, W+bias in registers,
// LDS = x-transpose dbuf ONLY, one lgkm-barrier per frame, spec frame-sum
// wave-local (dpp), mean via the W ones-row (q=129, wave 0 / tile 8).
// Block = 512 thr (8 waves) x 8 frames; grid (16, 32) = 512 blocks.
// ---------------------------------------------------------------------------
__global__ __launch_bounds__(512, 4) void k1_spec_mean(
    const float* __restrict__ x, const unsigned short* __restrict__ wb_ws,
    const float* __restrict__ bias_ws, float* __restrict__ out,
    unsigned short* __restrict__ spec_ws) {
  __shared__ __align__(16) unsigned short xbT[2][128 * 64];  // 32 KB dbuf

  const int tid = threadIdx.x;
  const int w = tid >> 6, lane = tid & 63;
  const int l15 = lane & 15, l4 = lane >> 4;
  const int g = tid >> 5, c16 = tid & 31;
  const int b = blockIdx.y;
  const int j0 = blockIdx.x * FPB;

  // W fragments + bias in registers: wave w owns tile w; wave 0 also tile 8.
  const int ntile = (w == 0) ? 2 : 1;
  bf16x8 wf[2][2];
  f32x4  bfr[2];
#pragma unroll
  for (int ti = 0; ti < 2; ++ti) {
    if (ti < ntile) {
      int tile = (ti == 0) ? w : 8;
#pragma unroll
      for (int kt = 0; kt < 2; ++kt)
        wf[ti][kt] = *(const bf16x8*)(wb_ws + (tile * 16 + l15) * 64 + kt * 32 + l4 * 8);
      bfr[ti] = *(const f32x4*)(bias_ws + tile * 16 + l4 * 4);
    }
  }

  i32x4 rx = make_srsrc_wave(x + (size_t)b * CH * T_);
  const int vxbase = (g * 4 * T_ + c16 * 4) * 4;  // rows 4g..4g+3, col c16*4

  f32x4 r[4];
#pragma unroll
  for (int it = 0; it < 4; ++it)
    r[it] = llvm_amdgcn_raw_buffer_load_v4f32(rx, vxbase + j0 * 512, it * (T_ * 4), 0);

#pragma unroll 2
  for (int f = 0; f < FPB; ++f) {
    const int j = j0 + f;
    char* xb = (char*)xbT + (f & 1) * 16384;

    // ---- pack r -> xbT[f&1] (bf16, swizzled), then prefetch frame f+1 ----
    {
      const int o8 = g >> 1, h = g & 1;
#pragma unroll
      for (int e = 0; e < 4; ++e) {
        int t = c16 * 4 + e;
        unsigned a = (unsigned)(t * 128 + o8 * 16 + h * 8);
        a ^= (unsigned)(((t ^ (t >> 3)) & 7) << 4);
        uint2 dv = make_uint2(pk2(r[0][e], r[1][e]), pk2(r[2][e], r[3][e]));
        *(uint2*)(xb + a) = dv;
      }
    }
    if (f < FPB - 1) {
#pragma unroll
      for (int it = 0; it < 4; ++it)
        r[it] = llvm_amdgcn_raw_buffer_load_v4f32(rx, vxbase + (j + 1) * 512, it * (T_ * 4), 0);
    }
    bar_lgkm();  // single barrier per frame; vmcnt NOT drained

    // ---- compute: D[q][t] = W*x^T, clip, wave-local frame-sum ----
    f32x4 sum[2];
    sum[0] = (f32x4){0.f, 0.f, 0.f, 0.f};
    sum[1] = (f32x4){0.f, 0.f, 0.f, 0.f};
#pragma unroll
    for (int tt = 0; tt < 8; ++tt) {
      int t = tt * 16 + l15;
      unsigned a0 = (unsigned)(t * 128 + l4 * 16);
      a0 ^= (unsigned)(((t ^ (t >> 3)) & 7) << 4);
      bf16x8 xb0 = *(const bf16x8*)(xb + a0);
      bf16x8 xb1 = *(const bf16x8*)(xb + (a0 ^ 64));
#pragma unroll
      for (int ti = 0; ti < 2; ++ti) {
        if (ti < ntile) {
          f32x4 acc = bfr[ti];
          acc = __builtin_amdgcn_mfma_f32_16x16x32_bf16(wf[ti][0], xb0, acc, 0, 0, 0);
          acc = __builtin_amdgcn_mfma_f32_16x16x32_bf16(wf[ti][1], xb1, acc, 0, 0, 0);
          if (ti == 1 && l4 == 0)  // q=129 ones-row: channel sum -> mean
            out[(size_t)b * T_ + (size_t)j * 128 + tt * 16 + l15] = acc[1] * (1.f / 64.f);
#pragma unroll
          for (int rr = 0; rr < 4; ++rr)
            sum[ti][rr] += __builtin_amdgcn_fmed3f(acc[rr], 0.f, 1.f);
        }
      }
    }
    // frame-mean reduce across the 16 t-cols (l15) via DPP; store 4 bf16.
    // Tile 8 guarded to l4<2 so q stays within QPAD (only q<=128 consumed).
    unsigned short* sp = spec_ws + ((size_t)b * NFRM + j) * QPAD;
#pragma unroll
    for (int ti = 0; ti < 2; ++ti) {
      if (ti < ntile) {
        int tile = (ti == 0) ? w : 8;
        float s0 = dpp_sum16(sum[ti][0]) * (1.f / 128.f);
        float s1 = dpp_sum16(sum[ti][1]) * (1.f / 128.f);
        float s2 = dpp_sum16(sum[ti][2]) * (1.f / 128.f);
        float s3 = dpp_sum16(sum[ti][3]) * (1.f / 128.f);
        if (l15 == 0 && (tile != 8 || l4 < 2)) {
          uint2 pv = make_uint2(pk2(s0, s1), pk2(s2, s3));
          *(uint2*)(sp + tile * 16 + l4 * 4) = pv;
        }
      }
    }
  }
}

// ---------------------------------------------------------------------------
// k2 (R6-proven, CHK=16): chunk = 16 frames -> grid (8, 32) = 256 blocks.
// Slots s=0..16 map to frames j = c*16-1+s (slot 0 = tail provider, spec=0
// for j<0). N padded to 32 slots (s>=17 zero).
// ---------------------------------------------------------------------------
__global__ __launch_bounds__(512) void k2_noise(
    const float* __restrict__ white, const unsigned short* __restrict__ spec_ws,
    const unsigned short* __restrict__ T1, const unsigned short* __restrict__ T2,
    const float* __restrict__ nf_p, float* __restrict__ out) {
  __shared__ __align__(16) unsigned short wn[4224];
  __shared__ __align__(16) unsigned short spec_l[32 * QPAD];
  __shared__ __align__(16) unsigned short G[32 * 256];
  __shared__ __align__(16) unsigned short audio[256 * 33];

  const int c = blockIdx.x, b = blockIdx.y;
  const int jb = c * CHK - 1;
  const int tid = threadIdx.x;
  const int lane = tid & 63, w = tid >> 6;
  const int l15 = lane & 15, l4 = lane >> 4;

  for (int rc = tid; rc < 528; rc += 512) {
    int g0 = jb * 128 + rc * 8;
    bf16x8 pk;
    if (rc < 288 && (unsigned)g0 < (unsigned)T_) {
      const float* wp = white + (size_t)b * T_ + g0;
      union { unsigned u[4]; bf16x8 h; } t;
#pragma unroll
      for (int p = 0; p < 4; ++p) t.u[p] = pk2(wp[2 * p], wp[2 * p + 1]);
      pk = t.h;
    } else {
#pragma unroll
      for (int e = 0; e < 8; ++e) pk[e] = 0;
    }
    unsigned a = rc * 16;
    a ^= ((a >> 8) & 7) << 4;
    *(bf16x8*)((char*)wn + a) = pk;
  }
  for (int ec = tid; ec < 32 * 17; ec += 512) {
    int s = ec / 17, cr = ec % 17;
    int jj = jb + s;
    uint4 vv = make_uint4(0u, 0u, 0u, 0u);
    if (s < 17 && (unsigned)jj < 128u)
      vv = *(const uint4*)(spec_ws + ((size_t)b * NFRM + jj) * QPAD + cr * 8);
    *(uint4*)(spec_l + s * QPAD + cr * 8) = vv;
  }
  __syncthreads();

  const f32x4 fz = {0.f, 0.f, 0.f, 0.f};
  f32x4 acc[2][2];
#pragma unroll
  for (int mi = 0; mi < 2; ++mi)
#pragma unroll
    for (int nt = 0; nt < 2; ++nt) acc[mi][nt] = fz;
#pragma unroll
  for (int kt = 0; kt < 8; ++kt) {
    bf16x8 bfr[2];
#pragma unroll
    for (int nt = 0; nt < 2; ++nt) {
      int s = nt * 16 + l15;
      unsigned a = s * 256 + kt * 64 + l4 * 16;
      a ^= ((a >> 8) & 7) << 4;
      bfr[nt] = *(const bf16x8*)((const char*)wn + a);
    }
#pragma unroll
    for (int mi = 0; mi < 2; ++mi) {
      int q = (2 * w + mi) * 16 + l15;
      bf16x8 afr = *(const bf16x8*)(T1 + q * 256 + kt * 32 + l4 * 8);
#pragma unroll
      for (int nt = 0; nt < 2; ++nt)
        acc[mi][nt] = __builtin_amdgcn_mfma_f32_16x16x32_bf16(afr, bfr[nt], acc[mi][nt], 0, 0, 0);
    }
  }
#pragma unroll
  for (int mi = 0; mi < 2; ++mi) {
    int qbase = (2 * w + mi) * 16 + l4 * 4;
#pragma unroll
    for (int nt = 0; nt < 2; ++nt) {
      int s = nt * 16 + l15;
#pragma unroll
      for (int rp = 0; rp < 2; ++rp) {
        int q0 = qbase + rp * 2;
        int kk0 = (q0 <= 128) ? q0 : q0 - 128;
        int kk1 = (q0 + 1 <= 128) ? q0 + 1 : q0 - 127;
        float s0 = b2f(spec_l[s * QPAD + kk0]);
        float s1 = b2f(spec_l[s * QPAD + kk1]);
        unsigned pw = pk2(acc[mi][nt][rp * 2] * s0, acc[mi][nt][rp * 2 + 1] * s1);
        unsigned a = s * 512 + q0 * 2;
        a ^= ((a >> 9) & 7) << 4;
        *(unsigned*)((char*)G + a) = pw;
      }
    }
  }
  __syncthreads();

  f32x4 acc2[2][2];
#pragma unroll
  for (int mi = 0; mi < 2; ++mi)
#pragma unroll
    for (int nt = 0; nt < 2; ++nt) acc2[mi][nt] = fz;
#pragma unroll
  for (int kt = 0; kt < 8; ++kt) {
    bf16x8 bfr[2];
#pragma unroll
    for (int nt = 0; nt < 2; ++nt) {
      int s = nt * 16 + l15;
      unsigned a = s * 512 + kt * 64 + l4 * 16;
      a ^= ((a >> 9) & 7) << 4;
      bfr[nt] = *(const bf16x8*)((const char*)G + a);
    }
#pragma unroll
    for (int mi = 0; mi < 2; ++mi) {
      int n = (2 * w + mi) * 16 + l15;
      bf16x8 afr = *(const bf16x8*)(T2 + n * 256 + kt * 32 + l4 * 8);
#pragma unroll
      for (int nt = 0; nt < 2; ++nt)
        acc2[mi][nt] = __builtin_amdgcn_mfma_f32_16x16x32_bf16(afr, bfr[nt], acc2[mi][nt], 0, 0, 0);
    }
  }
#pragma unroll
  for (int mi = 0; mi < 2; ++mi)
#pragma unroll
    for (int nt = 0; nt < 2; ++nt)
#pragma unroll
      for (int r = 0; r < 4; ++r) {
        int n = (2 * w + mi) * 16 + l4 * 4 + r;
        int s = nt * 16 + l15;
        audio[n * 33 + s] = f2bs(acc2[mi][nt][r]);
      }
  __syncthreads();

  const float cf = nf_p[0] * (1.f / 256.f);
  {
    int t0 = tid * 4;
    int n = t0 & 127, jl = t0 >> 7;
    int s1 = jl + 1;
    size_t o = (size_t)b * T_ + (size_t)c * (CHK * 128) + t0;
    f32x4 ov = *(f32x4*)(out + o);
#pragma unroll
    for (int e = 0; e < 4; ++e) {
      float a1 = b2f(audio[(n + e) * 33 + s1]);
      float a2 = b2f(audio[(n + e + 128) * 33 + jl]);
      ov[e] += cf * (a1 + a2);
    }
    *(f32x4*)(out + o) = ov;
  }
}

// ---------------------------------------------------------------------------
extern "C" void kernel_launch(void* const* d_in, const int* in_sizes, int n_in,
                              void* d_out, int out_size, void* d_ws, size_t ws_size,
                              hipStream_t stream) {
  (void)in_sizes; (void)n_in; (void)out_size; (void)ws_size;
  const float* x            = (const float*)d_in[0];
  const float* noise_w      = (const float*)d_in[5];
  const float* noise_b      = (const float*)d_in[6];
  const float* noise_factor = (const float*)d_in[7];
  const float* white        = (const float*)d_in[8];
  float* out = (float*)d_out;

  unsigned short* T1    = (unsigned short*)d_ws;             // 65536 bf16
  unsigned short* T2    = T1 + 65536;                        // 65536 bf16
  unsigned short* spec  = T2 + 65536;                        // 32*128*136 bf16
  unsigned short* wb_ws = spec + (size_t)B_ * NFRM * QPAD;   // 144*64 bf16 linear
  float*          bias_ws = (float*)(wb_ws + MROWS * 64);    // 144 f32

  k0_setup<<<69, 256, 0, stream>>>(T1, T2, noise_w, noise_b, wb_ws, bias_ws);
  k1_spec_mean<<<dim3(NFRM / FPB, B_), 512, 0, stream>>>(x, wb_ws, bias_ws, out, spec);
  k2_noise<<<dim3(T_ / (CHK * 128), B_), 512, 0, stream>>>(white, spec, T1, T2, noise_factor, out);
}